// Round 1
// baseline (591.094 us; speedup 1.0000x reference)
//
#include <hip/hip_runtime.h>

// SSIM_13443247637111 — fused separable SSIM, V-first ring-buffer design.
// B=16, CH=3, 512x512, 11x11 gaussian sigma 1.5, zero padding 5.
//
// Round-3 structure (occupancy fix):
//  - match/mask pipeline evicted from the hot kernel: a separate cheap
//    box-filter kernel precomputes mask bytes (and the full denominator
//    sum) once per batch image instead of once per (batch, channel).
//    Main kernel: 2 rings + 5 fld arrays -> LDS 25.5 KB -> 6 blocks/CU.
//  - STRIPH 256 -> 128, grid 8x4x48 = 1536 blocks = exactly 6 blocks/CU.
//  - __launch_bounds__(256, 6): cap VGPR alloc so registers don't gate
//    the 6-block residency (was 84 VGPR = 5 waves/SIMD cap).
//  - ws_size guard: if workspace can't hold the 4.2 MB mask, fall back
//    to the round-2 all-in-one kernel (proven, 246 us).

#define BATCH 16
#define CHANS 3
#define IMH 512
#define IMW 512
#define STRIPW 64
#define STRIPH 128
#define RINGR 18            // raw rows resident: y-5 .. y+12 for an 8-row super
#define LDSW 84             // padded row width; col c <-> x = bx*64 + c - 8
#define SUP 8               // output rows per super-iteration
#define NSUP (STRIPH / SUP) // 16
#define NQ 20               // float4 quads per staged row (80 cols)

// mask-pass tile
#define MTW 64
#define MTH 64
#define MRAWH 74            // MTH + 10 halo rows

__device__ __forceinline__ float4 ld4s(const float* p) { return *(const float4*)p; }
__device__ __forceinline__ void st4s(float* p, float4 v) { *(float4*)p = v; }
__device__ __forceinline__ void fma4(float4& a, float w, float4 x) {
    a.x = fmaf(w, x.x, a.x); a.y = fmaf(w, x.y, a.y);
    a.z = fmaf(w, x.z, a.z); a.w = fmaf(w, x.w, a.w);
}
__device__ __forceinline__ void fma4m(float4& a, float w, float4 x, float4 y) {
    a.x = fmaf(w, x.x * y.x, a.x); a.y = fmaf(w, x.y * y.y, a.y);
    a.z = fmaf(w, x.z * y.z, a.z); a.w = fmaf(w, x.w * y.w, a.w);
}
__device__ __forceinline__ void add4(float4& a, float4 x) {
    a.x += x.x; a.y += x.y; a.z += x.z; a.w += x.w;
}

// gaussian-weighted horizontal 11-tap conv: 4 outputs from 20-float window
__device__ __forceinline__ void convg(const float* __restrict__ row, int cb,
                                      const float* __restrict__ g, float out[4]) {
    float w[20];
    #pragma unroll
    for (int i = 0; i < 5; ++i) {
        float4 v = ld4s(row + cb + 4 * i);
        w[4*i+0] = v.x; w[4*i+1] = v.y; w[4*i+2] = v.z; w[4*i+3] = v.w;
    }
    #pragma unroll
    for (int j = 0; j < 4; ++j) {
        float a = 0.0f;
        #pragma unroll
        for (int k = 0; k < 11; ++k) a = fmaf(g[k], w[3 + j + k], a);
        out[j] = a;
    }
}

// unweighted (box) horizontal 11-tap sum
__device__ __forceinline__ void convb(const float* __restrict__ row, int cb,
                                      float out[4]) {
    float w[20];
    #pragma unroll
    for (int i = 0; i < 5; ++i) {
        float4 v = ld4s(row + cb + 4 * i);
        w[4*i+0] = v.x; w[4*i+1] = v.y; w[4*i+2] = v.z; w[4*i+3] = v.w;
    }
    #pragma unroll
    for (int j = 0; j < 4; ++j) {
        float a = 0.0f;
        #pragma unroll
        for (int k = 0; k < 11; ++k) a += w[3 + j + k];
        out[j] = a;
    }
}

// ---------------------------------------------------------------------------
// mask precompute: box-filter match (11x11), threshold, store uint8 per pixel.
// Also accumulates the full denominator sum(mask) into acc[1].
// Grid 8x8x16 = 1024 blocks; ~21 MB of traffic, L2/L3-resident -> ~10 us.
// ---------------------------------------------------------------------------
__global__ __launch_bounds__(256) void mask_pass(
    const float* __restrict__ match, unsigned char* __restrict__ maskbuf,
    double* __restrict__ acc)
{
    __shared__ __align__(16) float raw[MRAWH][LDSW];
    __shared__ __align__(16) float vs[MTH][LDSW];
    __shared__ float red[4];

    const int tid = threadIdx.x;
    const int b = blockIdx.z;
    const int x0 = blockIdx.x * MTW - 8;     // global x of LDS col 0 (aligned)
    const int y0 = blockIdx.y * MTH - 5;
    const float* pm = match + (size_t)b * (IMH * IMW);

    // stage 74 rows x 20 quads (cols x0 .. x0+79), zero pad OOB
    for (int t = tid; t < MRAWH * NQ; t += 256) {
        int r = t / NQ, q = t - r * NQ;
        int gy = y0 + r;
        int gx = x0 + 4 * q;
        float4 v = make_float4(0.f, 0.f, 0.f, 0.f);
        if ((unsigned)gy < IMH) {
            if ((unsigned)gx <= (IMW - 4)) {
                v = ld4s(pm + gy * IMW + gx);
            } else {
                float tmp[4];
                #pragma unroll
                for (int e = 0; e < 4; ++e) {
                    int x = gx + e;
                    bool ok = (unsigned)x < IMW;
                    tmp[e] = ok ? pm[gy * IMW + x] : 0.0f;
                }
                v = make_float4(tmp[0], tmp[1], tmp[2], tmp[3]);
            }
        }
        st4s(&raw[r][4 * q], v);
    }
    __syncthreads();

    // vertical box: 64 rows x 20 quads
    for (int t = tid; t < MTH * NQ; t += 256) {
        int r = t / NQ, q = t - r * NQ;
        int cq = 4 * q;
        float4 a = make_float4(0.f, 0.f, 0.f, 0.f);
        #pragma unroll
        for (int k = 0; k < 11; ++k) add4(a, ld4s(&raw[r + k][cq]));
        st4s(&vs[r][cq], a);
    }
    __syncthreads();

    // horizontal box + threshold: 64 rows x 16 quads
    float den = 0.0f;
    for (int t = tid; t < MTH * 16; t += 256) {
        int r = t >> 4, q = t & 15;
        float mb[4];
        convb(vs[r], 4 * q, mb);
        unsigned char bits[4];
        #pragma unroll
        for (int j = 0; j < 4; ++j) {
            float m = mb[j] * (1.0f / 121.0f) + 1e-7f;
            bool on = m > 0.5f;
            bits[j] = (unsigned char)on;
            den += on ? (1.0f + 1e-7f) : 1e-7f;
        }
        int gy = blockIdx.y * MTH + r;
        int gx = blockIdx.x * MTW + 4 * q;
        *(uchar4*)(maskbuf + ((size_t)b << 18) + (gy << 9) + gx) =
            make_uchar4(bits[0], bits[1], bits[2], bits[3]);
    }

    for (int off = 32; off > 0; off >>= 1) den += __shfl_down(den, off);
    if ((tid & 63) == 0) red[tid >> 6] = den;
    __syncthreads();
    if (tid == 0)
        atomicAdd(&acc[1], (double)(red[0] + red[1] + red[2] + red[3]));
}

// ---------------------------------------------------------------------------
// main SSIM kernel, premask variant: 2 rings + 5 fld arrays, LDS 25.5 KB,
// 6 blocks/CU residency. Grid 8x4x48 = 1536 = exactly 6 blocks/CU.
// ---------------------------------------------------------------------------
__global__ __launch_bounds__(256, 6) void ssim_main_pm(
    const float* __restrict__ img1, const float* __restrict__ img2,
    const unsigned char* __restrict__ maskbuf, double* __restrict__ acc)
{
    __shared__ __align__(16) float ring1[RINGR][LDSW];
    __shared__ __align__(16) float ring2[RINGR][LDSW];
    __shared__ __align__(16) float fld[5][SUP][LDSW];
    __shared__ float redn[4];

    const int tid = threadIdx.x;
    const int bc = blockIdx.z;
    const int b = bc / CHANS;
    const int c = bc - b * CHANS;
    const int ystart = blockIdx.y * STRIPH;
    const int bxg = blockIdx.x;
    const int bx0 = bxg * STRIPW - 8;   // global x of LDS col 0

    const float* p1 = img1 + (size_t)(b * CHANS + c) * (IMH * IMW);
    const float* p2 = img2 + (size_t)(b * CHANS + c) * (IMH * IMW);
    const unsigned char* pmk = maskbuf + ((size_t)b << 18);

    // normalized gaussian weights (expf matches reference to fp noise)
    float g[11];
    {
        float s = 0.0f;
        #pragma unroll
        for (int i = 0; i < 11; ++i) {
            float d = (float)(i - 5);
            g[i] = expf(-(d * d) / 4.5f);
            s += g[i];
        }
        #pragma unroll
        for (int i = 0; i < 11; ++i) g[i] /= s;
    }

    float num = 0.0f;
    const bool colsafe = (bx0 >= 0) && (bx0 + 4 * NQ <= IMW);  // interior in x

    auto stage = [&](int gy0, int nrows) {
        // nrows*NQ <= 200 < 256: single shot, no loop
        if (tid < nrows * NQ) {
            int r = tid / NQ, q = tid - r * NQ;
            int gy = gy0 + r;
            int slot = (gy + 36) % RINGR;
            int gx = bx0 + 4 * q;
            float4 v1 = make_float4(0.f, 0.f, 0.f, 0.f), v2 = v1;
            if ((unsigned)gy < IMH) {
                if (colsafe || (unsigned)gx <= (IMW - 4)) {
                    v1 = ld4s(p1 + gy * IMW + gx);
                    v2 = ld4s(p2 + gy * IMW + gx);
                } else {
                    float t1[4], t2[4];
                    #pragma unroll
                    for (int e = 0; e < 4; ++e) {
                        int x = gx + e;
                        bool ok = (unsigned)x < IMW;
                        int off = gy * IMW + (ok ? x : 0);
                        t1[e] = ok ? p1[off] : 0.0f;
                        t2[e] = ok ? p2[off] : 0.0f;
                    }
                    v1 = make_float4(t1[0], t1[1], t1[2], t1[3]);
                    v2 = make_float4(t2[0], t2[1], t2[2], t2[3]);
                }
            }
            st4s(&ring1[slot][4 * q], v1);
            st4s(&ring2[slot][4 * q], v2);
        }
    };

    // prologue: raw rows ystart-5 .. ystart+4
    stage(ystart - 5, 10);

    for (int s = 0; s < NSUP; ++s) {
        const int ybase = ystart + s * SUP;

        // stage the 8 new raw rows this super needs (ybase+5 .. ybase+12).
        // safe: slots being overwritten were last read by V of super s-1,
        // which completed before barrier B2 of super s-1.
        stage(ybase + 5, SUP);
        __syncthreads();   // B1: staging visible; fld free (H of s-1 done)

        // ---- vertical pass: 8 rows x 20 quads (80 cols incl. halo) ----
        if (tid < SUP * NQ) {
            int r = tid / NQ, q = tid - r * NQ;
            int cq = 4 * q;
            int sr = (ybase + r + 31) % RINGR;   // row (y-5)
            float4 a1 = make_float4(0,0,0,0), a2 = a1, a3 = a1,
                   a4 = a1, a5 = a1;
            #pragma unroll
            for (int k = 0; k < 11; ++k) {
                float4 x1 = ld4s(&ring1[sr][cq]);
                float4 x2 = ld4s(&ring2[sr][cq]);
                float w = g[k];
                fma4(a1, w, x1);
                fma4(a2, w, x2);
                fma4m(a3, w, x1, x1);
                fma4m(a4, w, x2, x2);
                fma4m(a5, w, x1, x2);
                sr++; if (sr >= RINGR) sr -= RINGR;
            }
            st4s(&fld[0][r][cq], a1);
            st4s(&fld[1][r][cq], a2);
            st4s(&fld[2][r][cq], a3);
            st4s(&fld[3][r][cq], a4);
            st4s(&fld[4][r][cq], a5);
        }
        __syncthreads();   // B2: fld visible; ring free for next stage

        // ---- horizontal pass + SSIM: 8 rows x 16 quads (64 cols) ----
        if (tid < SUP * 16) {
            int r = tid >> 4, q = tid & 15;
            int cb = 4 * q;   // window w[0] = col 4q; outputs at cols 4q+8..11
            float mu1[4], mu2[4], m11[4], m22[4], m12[4];
            convg(fld[0][r], cb, g, mu1);
            convg(fld[1][r], cb, g, mu2);
            convg(fld[2][r], cb, g, m11);
            convg(fld[3][r], cb, g, m22);
            convg(fld[4][r], cb, g, m12);
            int gy = ybase + r;
            int gx = bxg * STRIPW + cb;
            uchar4 mk = *(const uchar4*)(pmk + (gy << 9) + gx);
            const unsigned char mkv[4] = {mk.x, mk.y, mk.z, mk.w};
            #pragma unroll
            for (int j = 0; j < 4; ++j) {
                float mu1s = mu1[j] * mu1[j];
                float mu2s = mu2[j] * mu2[j];
                float mu12 = mu1[j] * mu2[j];
                float sg1  = m11[j] - mu1s;
                float sg2  = m22[j] - mu2s;
                float sg12 = m12[j] - mu12;
                float ssim = ((2.0f * mu12 + 1e-4f) * (2.0f * sg12 + 9e-4f)) /
                             ((mu1s + mu2s + 1e-4f) * (sg1 + sg2 + 9e-4f));
                float mask = mkv[j] ? (1.0f + 1e-7f) : 1e-7f;
                num += (1.0f - ssim) * mask;
            }
        }
    }

    // ---- block reduction: wave shuffle (width 64) then cross-wave LDS ----
    for (int off = 32; off > 0; off >>= 1) num += __shfl_down(num, off);
    if ((tid & 63) == 0) redn[tid >> 6] = num;
    __syncthreads();
    if (tid == 0)
        atomicAdd(&acc[0], (double)(redn[0] + redn[1] + redn[2] + redn[3]));
    (void)c;
}

// ---------------------------------------------------------------------------
// fallback: round-2 all-in-one kernel (used only if ws too small for mask)
// ---------------------------------------------------------------------------
__global__ __launch_bounds__(256) void ssim_main_fb(
    const float* __restrict__ img1, const float* __restrict__ img2,
    const float* __restrict__ match, double* __restrict__ acc)
{
    __shared__ __align__(16) float ring1[RINGR][LDSW];
    __shared__ __align__(16) float ring2[RINGR][LDSW];
    __shared__ __align__(16) float ringm[RINGR][LDSW];
    __shared__ __align__(16) float fld[6][SUP][LDSW];
    __shared__ float redn[4], redd[4];

    const int tid = threadIdx.x;
    const int bc = blockIdx.z;
    const int b = bc / CHANS;
    const int c = bc - b * CHANS;
    const int ystart = blockIdx.y * STRIPH;
    const int bx0 = blockIdx.x * STRIPW - 8;

    const float* p1 = img1 + (size_t)(b * CHANS + c) * (IMH * IMW);
    const float* p2 = img2 + (size_t)(b * CHANS + c) * (IMH * IMW);
    const float* pm = match + (size_t)b * (IMH * IMW);

    float g[11];
    {
        float s = 0.0f;
        #pragma unroll
        for (int i = 0; i < 11; ++i) {
            float d = (float)(i - 5);
            g[i] = expf(-(d * d) / 4.5f);
            s += g[i];
        }
        #pragma unroll
        for (int i = 0; i < 11; ++i) g[i] /= s;
    }

    float num = 0.0f, den = 0.0f;

    auto stage = [&](int gy0, int nrows) {
        for (int t = tid; t < nrows * NQ; t += 256) {
            int r = t / NQ, q = t - r * NQ;
            int gy = gy0 + r;
            int slot = (gy + 36) % RINGR;
            int gx = bx0 + 4 * q;
            float4 v1, v2, vm;
            if ((unsigned)gy < IMH && (unsigned)gx <= (IMW - 4)) {
                v1 = ld4s(p1 + gy * IMW + gx);
                v2 = ld4s(p2 + gy * IMW + gx);
                vm = ld4s(pm + gy * IMW + gx);
            } else if ((unsigned)gy < IMH) {
                float t1[4], t2[4], tm[4];
                #pragma unroll
                for (int e = 0; e < 4; ++e) {
                    int x = gx + e;
                    bool ok = (unsigned)x < IMW;
                    int off = gy * IMW + (ok ? x : 0);
                    t1[e] = ok ? p1[off] : 0.0f;
                    t2[e] = ok ? p2[off] : 0.0f;
                    tm[e] = ok ? pm[off] : 0.0f;
                }
                v1 = make_float4(t1[0], t1[1], t1[2], t1[3]);
                v2 = make_float4(t2[0], t2[1], t2[2], t2[3]);
                vm = make_float4(tm[0], tm[1], tm[2], tm[3]);
            } else {
                v1 = v2 = vm = make_float4(0.f, 0.f, 0.f, 0.f);
            }
            st4s(&ring1[slot][4 * q], v1);
            st4s(&ring2[slot][4 * q], v2);
            st4s(&ringm[slot][4 * q], vm);
        }
    };

    stage(ystart - 5, 10);

    for (int s = 0; s < NSUP; ++s) {
        const int ybase = ystart + s * SUP;
        stage(ybase + 5, SUP);
        __syncthreads();

        if (tid < SUP * NQ) {
            int r = tid / NQ, q = tid - r * NQ;
            int cq = 4 * q;
            int sr = (ybase + r + 31) % RINGR;
            float4 a1 = make_float4(0,0,0,0), a2 = a1, a3 = a1,
                   a4 = a1, a5 = a1, am = a1;
            #pragma unroll
            for (int k = 0; k < 11; ++k) {
                float4 x1 = ld4s(&ring1[sr][cq]);
                float4 x2 = ld4s(&ring2[sr][cq]);
                float4 xm = ld4s(&ringm[sr][cq]);
                float w = g[k];
                fma4(a1, w, x1);
                fma4(a2, w, x2);
                fma4m(a3, w, x1, x1);
                fma4m(a4, w, x2, x2);
                fma4m(a5, w, x1, x2);
                add4(am, xm);
                sr++; if (sr >= RINGR) sr -= RINGR;
            }
            st4s(&fld[0][r][cq], a1);
            st4s(&fld[1][r][cq], a2);
            st4s(&fld[2][r][cq], a3);
            st4s(&fld[3][r][cq], a4);
            st4s(&fld[4][r][cq], a5);
            st4s(&fld[5][r][cq], am);
        }
        __syncthreads();

        if (tid < SUP * 16) {
            int r = tid >> 4, q = tid & 15;
            int cb = 4 * q;
            float mu1[4], mu2[4], m11[4], m22[4], m12[4], mb[4];
            convg(fld[0][r], cb, g, mu1);
            convg(fld[1][r], cb, g, mu2);
            convg(fld[2][r], cb, g, m11);
            convg(fld[3][r], cb, g, m22);
            convg(fld[4][r], cb, g, m12);
            convb(fld[5][r], cb, mb);
            #pragma unroll
            for (int j = 0; j < 4; ++j) {
                float mu1s = mu1[j] * mu1[j];
                float mu2s = mu2[j] * mu2[j];
                float mu12 = mu1[j] * mu2[j];
                float sg1  = m11[j] - mu1s;
                float sg2  = m22[j] - mu2s;
                float sg12 = m12[j] - mu12;
                float ssim = ((2.0f * mu12 + 1e-4f) * (2.0f * sg12 + 9e-4f)) /
                             ((mu1s + mu2s + 1e-4f) * (sg1 + sg2 + 9e-4f));
                float m = mb[j] * (1.0f / 121.0f) + 1e-7f;
                float mask = (m > 0.5f) ? (1.0f + 1e-7f) : 1e-7f;
                num += (1.0f - ssim) * mask;
                den += mask;
            }
        }
    }

    for (int off = 32; off > 0; off >>= 1) {
        num += __shfl_down(num, off);
        den += __shfl_down(den, off);
    }
    int wave = tid >> 6;
    int lane = tid & 63;
    if (lane == 0) { redn[wave] = num; redd[wave] = den; }
    __syncthreads();
    if (tid == 0) {
        float n = redn[0] + redn[1] + redn[2] + redn[3];
        atomicAdd(&acc[0], (double)n);
        if (c == 0) {
            float d = redd[0] + redd[1] + redd[2] + redd[3];
            atomicAdd(&acc[1], (double)d);
        }
    }
}

__global__ void init_acc(double* acc) {
    acc[0] = 0.0;
    acc[1] = 0.0;
}

__global__ void finalize(const double* __restrict__ acc, float* __restrict__ out) {
    out[0] = (float)(acc[0] / acc[1] / 3.0);
}

extern "C" void kernel_launch(void* const* d_in, const int* in_sizes, int n_in,
                              void* d_out, int out_size, void* d_ws, size_t ws_size,
                              hipStream_t stream) {
    const float* img1  = (const float*)d_in[0];
    const float* img2  = (const float*)d_in[1];
    const float* match = (const float*)d_in[2];
    float* out = (float*)d_out;
    double* acc = (double*)d_ws;

    init_acc<<<1, 1, 0, stream>>>(acc);

    const size_t mask_need = 64 + (size_t)BATCH * IMH * IMW;  // 4,194,368 B
    dim3 block(256, 1, 1);
    if (ws_size >= mask_need) {
        unsigned char* mbuf = (unsigned char*)d_ws + 64;
        dim3 mgrid(IMW / MTW, IMH / MTH, BATCH);               // 8 x 8 x 16
        mask_pass<<<mgrid, block, 0, stream>>>(match, mbuf, acc);
        dim3 grid(IMW / STRIPW, IMH / STRIPH, BATCH * CHANS);  // 8 x 4 x 48
        ssim_main_pm<<<grid, block, 0, stream>>>(img1, img2, mbuf, acc);
    } else {
        dim3 grid(IMW / STRIPW, IMH / STRIPH, BATCH * CHANS);
        ssim_main_fb<<<grid, block, 0, stream>>>(img1, img2, match, acc);
    }

    finalize<<<1, 1, 0, stream>>>(acc, out);
}

// Round 3
// 260.750 us; speedup vs baseline: 2.2669x; 2.2669x over previous
//
#include <hip/hip_runtime.h>

// SSIM_13443247637111 — fused separable SSIM, V-first ring-buffer design.
// B=16, CH=3, 512x512, 11x11 gaussian sigma 1.5, zero padding 5.
//
// Round-5 = Round-4 resubmit (round-4 bench was an infra failure: container
// acquisition died twice; no kernel verdict was produced).
//
// Structure (spill fix + SGPR weights):
//  - ROUND-3 POST-MORTEM: __launch_bounds__(256,6) squeezed VGPRs to 40 ->
//    1.5 GB of scratch spill traffic (FETCH 593 MB, WRITE 938 MB). Residency
//    rose (62% occ) but each wave drowned in spills. Min-waves clause REMOVED.
//  - gaussian weights computed ONCE in init kernel (identical device expf
//    sequence -> bit-identical values) into workspace; hot kernels read them
//    via uniform pointer + constant offsets -> s_load into SGPRs. Frees ~11
//    persistent VGPRs, targeting the <=64-VGPR occupancy step so the LDS cap
//    (25.5 KB -> 6 blocks/CU), not registers, gates residency.
//  - STRIPH 64: grid 8x8x48 = 3072 blocks = exactly 12/CU -> whole dispatch
//    tiles evenly at either 4/CU (3 waves) or 6/CU (2 waves) residency.
//  - mask precompute kernel (box-filter match -> uint8, + full denominator
//    sum). ws guard falls back to round-2 all-in-one kernel.

#define BATCH 16
#define CHANS 3
#define IMH 512
#define IMW 512
#define STRIPW 64
#define STRIPH 64
#define RINGR 18            // raw rows resident: y-5 .. y+12 for an 8-row super
#define LDSW 84             // padded row width; col c <-> x = bx*64 + c - 8
#define SUP 8               // output rows per super-iteration
#define NSUP (STRIPH / SUP) // 8
#define NQ 20               // float4 quads per staged row (80 cols)

// mask-pass tile
#define MTW 64
#define MTH 64
#define MRAWH 74            // MTH + 10 halo rows

__device__ __forceinline__ float4 ld4s(const float* p) { return *(const float4*)p; }
__device__ __forceinline__ void st4s(float* p, float4 v) { *(float4*)p = v; }
__device__ __forceinline__ void fma4(float4& a, float w, float4 x) {
    a.x = fmaf(w, x.x, a.x); a.y = fmaf(w, x.y, a.y);
    a.z = fmaf(w, x.z, a.z); a.w = fmaf(w, x.w, a.w);
}
__device__ __forceinline__ void fma4m(float4& a, float w, float4 x, float4 y) {
    a.x = fmaf(w, x.x * y.x, a.x); a.y = fmaf(w, x.y * y.y, a.y);
    a.z = fmaf(w, x.z * y.z, a.z); a.w = fmaf(w, x.w * y.w, a.w);
}
__device__ __forceinline__ void add4(float4& a, float4 x) {
    a.x += x.x; a.y += x.y; a.z += x.z; a.w += x.w;
}

// gaussian-weighted horizontal 11-tap conv: 4 outputs from 20-float window
__device__ __forceinline__ void convg(const float* __restrict__ row, int cb,
                                      const float* __restrict__ g, float out[4]) {
    float w[20];
    #pragma unroll
    for (int i = 0; i < 5; ++i) {
        float4 v = ld4s(row + cb + 4 * i);
        w[4*i+0] = v.x; w[4*i+1] = v.y; w[4*i+2] = v.z; w[4*i+3] = v.w;
    }
    #pragma unroll
    for (int j = 0; j < 4; ++j) {
        float a = 0.0f;
        #pragma unroll
        for (int k = 0; k < 11; ++k) a = fmaf(g[k], w[3 + j + k], a);
        out[j] = a;
    }
}

// unweighted (box) horizontal 11-tap sum
__device__ __forceinline__ void convb(const float* __restrict__ row, int cb,
                                      float out[4]) {
    float w[20];
    #pragma unroll
    for (int i = 0; i < 5; ++i) {
        float4 v = ld4s(row + cb + 4 * i);
        w[4*i+0] = v.x; w[4*i+1] = v.y; w[4*i+2] = v.z; w[4*i+3] = v.w;
    }
    #pragma unroll
    for (int j = 0; j < 4; ++j) {
        float a = 0.0f;
        #pragma unroll
        for (int k = 0; k < 11; ++k) a += w[3 + j + k];
        out[j] = a;
    }
}

// ---------------------------------------------------------------------------
// mask precompute: box-filter match (11x11), threshold, store uint8 per pixel.
// Also accumulates the full denominator sum(mask) into acc[1].
// Grid 8x8x16 = 1024 blocks; ~21 MB of traffic, L2/L3-resident.
// ---------------------------------------------------------------------------
__global__ __launch_bounds__(256) void mask_pass(
    const float* __restrict__ match, unsigned char* __restrict__ maskbuf,
    double* __restrict__ acc)
{
    __shared__ __align__(16) float raw[MRAWH][LDSW];
    __shared__ __align__(16) float vs[MTH][LDSW];
    __shared__ float red[4];

    const int tid = threadIdx.x;
    const int b = blockIdx.z;
    const int x0 = blockIdx.x * MTW - 8;     // global x of LDS col 0 (aligned)
    const int y0 = blockIdx.y * MTH - 5;
    const float* pm = match + (size_t)b * (IMH * IMW);

    // stage 74 rows x 20 quads (cols x0 .. x0+79), zero pad OOB
    for (int t = tid; t < MRAWH * NQ; t += 256) {
        int r = t / NQ, q = t - r * NQ;
        int gy = y0 + r;
        int gx = x0 + 4 * q;
        float4 v = make_float4(0.f, 0.f, 0.f, 0.f);
        if ((unsigned)gy < IMH) {
            if ((unsigned)gx <= (IMW - 4)) {
                v = ld4s(pm + gy * IMW + gx);
            } else {
                float tmp[4];
                #pragma unroll
                for (int e = 0; e < 4; ++e) {
                    int x = gx + e;
                    bool ok = (unsigned)x < IMW;
                    tmp[e] = ok ? pm[gy * IMW + x] : 0.0f;
                }
                v = make_float4(tmp[0], tmp[1], tmp[2], tmp[3]);
            }
        }
        st4s(&raw[r][4 * q], v);
    }
    __syncthreads();

    // vertical box: 64 rows x 20 quads
    for (int t = tid; t < MTH * NQ; t += 256) {
        int r = t / NQ, q = t - r * NQ;
        int cq = 4 * q;
        float4 a = make_float4(0.f, 0.f, 0.f, 0.f);
        #pragma unroll
        for (int k = 0; k < 11; ++k) add4(a, ld4s(&raw[r + k][cq]));
        st4s(&vs[r][cq], a);
    }
    __syncthreads();

    // horizontal box + threshold: 64 rows x 16 quads
    float den = 0.0f;
    for (int t = tid; t < MTH * 16; t += 256) {
        int r = t >> 4, q = t & 15;
        float mb[4];
        convb(vs[r], 4 * q, mb);
        unsigned char bits[4];
        #pragma unroll
        for (int j = 0; j < 4; ++j) {
            float m = mb[j] * (1.0f / 121.0f) + 1e-7f;
            bool on = m > 0.5f;
            bits[j] = (unsigned char)on;
            den += on ? (1.0f + 1e-7f) : 1e-7f;
        }
        int gy = blockIdx.y * MTH + r;
        int gx = blockIdx.x * MTW + 4 * q;
        *(uchar4*)(maskbuf + ((size_t)b << 18) + (gy << 9) + gx) =
            make_uchar4(bits[0], bits[1], bits[2], bits[3]);
    }

    for (int off = 32; off > 0; off >>= 1) den += __shfl_down(den, off);
    if ((tid & 63) == 0) red[tid >> 6] = den;
    __syncthreads();
    if (tid == 0)
        atomicAdd(&acc[1], (double)(red[0] + red[1] + red[2] + red[3]));
}

// ---------------------------------------------------------------------------
// main SSIM kernel, premask variant: 2 rings + 5 fld arrays, LDS 25.5 KB.
// NO min-waves launch bound (round-3 spill lesson). Weights from ws (SGPRs).
// Grid 8x8x48 = 3072 blocks = exactly 12/CU.
// ---------------------------------------------------------------------------
__global__ __launch_bounds__(256) void ssim_main_pm(
    const float* __restrict__ img1, const float* __restrict__ img2,
    const unsigned char* __restrict__ maskbuf,
    const float* __restrict__ gw, double* __restrict__ acc)
{
    __shared__ __align__(16) float ring1[RINGR][LDSW];
    __shared__ __align__(16) float ring2[RINGR][LDSW];
    __shared__ __align__(16) float fld[5][SUP][LDSW];
    __shared__ float redn[4];

    const int tid = threadIdx.x;
    const int bc = blockIdx.z;
    const int b = bc / CHANS;
    const int c = bc - b * CHANS;
    const int ystart = blockIdx.y * STRIPH;
    const int bxg = blockIdx.x;
    const int bx0 = bxg * STRIPW - 8;   // global x of LDS col 0

    const float* p1 = img1 + (size_t)(b * CHANS + c) * (IMH * IMW);
    const float* p2 = img2 + (size_t)(b * CHANS + c) * (IMH * IMW);
    const unsigned char* pmk = maskbuf + ((size_t)b << 18);

    // weights: uniform pointer + constant offsets -> scalar loads (SGPRs),
    // bit-identical to the expf sequence the reference-matched kernels used.
    float g[11];
    #pragma unroll
    for (int i = 0; i < 11; ++i) g[i] = gw[i];

    float num = 0.0f;
    const bool colsafe = (bx0 >= 0) && (bx0 + 4 * NQ <= IMW);  // interior in x

    auto stage = [&](int gy0, int nrows) {
        // nrows*NQ <= 200 < 256: single shot, no loop
        if (tid < nrows * NQ) {
            int r = tid / NQ, q = tid - r * NQ;
            int gy = gy0 + r;
            int slot = (gy + 36) % RINGR;
            int gx = bx0 + 4 * q;
            float4 v1 = make_float4(0.f, 0.f, 0.f, 0.f), v2 = v1;
            if ((unsigned)gy < IMH) {
                if (colsafe || (unsigned)gx <= (IMW - 4)) {
                    v1 = ld4s(p1 + gy * IMW + gx);
                    v2 = ld4s(p2 + gy * IMW + gx);
                } else {
                    float t1[4], t2[4];
                    #pragma unroll
                    for (int e = 0; e < 4; ++e) {
                        int x = gx + e;
                        bool ok = (unsigned)x < IMW;
                        int off = gy * IMW + (ok ? x : 0);
                        t1[e] = ok ? p1[off] : 0.0f;
                        t2[e] = ok ? p2[off] : 0.0f;
                    }
                    v1 = make_float4(t1[0], t1[1], t1[2], t1[3]);
                    v2 = make_float4(t2[0], t2[1], t2[2], t2[3]);
                }
            }
            st4s(&ring1[slot][4 * q], v1);
            st4s(&ring2[slot][4 * q], v2);
        }
    };

    // prologue: raw rows ystart-5 .. ystart+4
    stage(ystart - 5, 10);

    for (int s = 0; s < NSUP; ++s) {
        const int ybase = ystart + s * SUP;

        // stage the 8 new raw rows this super needs (ybase+5 .. ybase+12).
        // safe: slots being overwritten were last read by V of super s-1,
        // which completed before barrier B2 of super s-1.
        stage(ybase + 5, SUP);
        __syncthreads();   // B1: staging visible; fld free (H of s-1 done)

        // ---- vertical pass: 8 rows x 20 quads (80 cols incl. halo) ----
        if (tid < SUP * NQ) {
            int r = tid / NQ, q = tid - r * NQ;
            int cq = 4 * q;
            int sr = (ybase + r + 31) % RINGR;   // row (y-5)
            float4 a1 = make_float4(0,0,0,0), a2 = a1, a3 = a1,
                   a4 = a1, a5 = a1;
            #pragma unroll
            for (int k = 0; k < 11; ++k) {
                float4 x1 = ld4s(&ring1[sr][cq]);
                float4 x2 = ld4s(&ring2[sr][cq]);
                float w = g[k];
                fma4(a1, w, x1);
                fma4(a2, w, x2);
                fma4m(a3, w, x1, x1);
                fma4m(a4, w, x2, x2);
                fma4m(a5, w, x1, x2);
                sr++; if (sr >= RINGR) sr -= RINGR;
            }
            st4s(&fld[0][r][cq], a1);
            st4s(&fld[1][r][cq], a2);
            st4s(&fld[2][r][cq], a3);
            st4s(&fld[3][r][cq], a4);
            st4s(&fld[4][r][cq], a5);
        }
        __syncthreads();   // B2: fld visible; ring free for next stage

        // ---- horizontal pass + SSIM: 8 rows x 16 quads (64 cols) ----
        if (tid < SUP * 16) {
            int r = tid >> 4, q = tid & 15;
            int cb = 4 * q;   // window w[0] = col 4q; outputs at cols 4q+8..11
            float mu1[4], mu2[4], m11[4], m22[4], m12[4];
            convg(fld[0][r], cb, g, mu1);
            convg(fld[1][r], cb, g, mu2);
            convg(fld[2][r], cb, g, m11);
            convg(fld[3][r], cb, g, m22);
            convg(fld[4][r], cb, g, m12);
            int gy = ybase + r;
            int gx = bxg * STRIPW + cb;
            uchar4 mk = *(const uchar4*)(pmk + (gy << 9) + gx);
            const unsigned char mkv[4] = {mk.x, mk.y, mk.z, mk.w};
            #pragma unroll
            for (int j = 0; j < 4; ++j) {
                float mu1s = mu1[j] * mu1[j];
                float mu2s = mu2[j] * mu2[j];
                float mu12 = mu1[j] * mu2[j];
                float sg1  = m11[j] - mu1s;
                float sg2  = m22[j] - mu2s;
                float sg12 = m12[j] - mu12;
                float ssim = ((2.0f * mu12 + 1e-4f) * (2.0f * sg12 + 9e-4f)) /
                             ((mu1s + mu2s + 1e-4f) * (sg1 + sg2 + 9e-4f));
                float mask = mkv[j] ? (1.0f + 1e-7f) : 1e-7f;
                num += (1.0f - ssim) * mask;
            }
        }
    }

    // ---- block reduction: wave shuffle (width 64) then cross-wave LDS ----
    for (int off = 32; off > 0; off >>= 1) num += __shfl_down(num, off);
    if ((tid & 63) == 0) redn[tid >> 6] = num;
    __syncthreads();
    if (tid == 0)
        atomicAdd(&acc[0], (double)(redn[0] + redn[1] + redn[2] + redn[3]));
    (void)c;
}

// ---------------------------------------------------------------------------
// fallback: round-2 all-in-one kernel (used only if ws too small for mask)
// ---------------------------------------------------------------------------
#define FBSTRIPH 256
#define FBNSUP (FBSTRIPH / SUP)
__global__ __launch_bounds__(256) void ssim_main_fb(
    const float* __restrict__ img1, const float* __restrict__ img2,
    const float* __restrict__ match, double* __restrict__ acc)
{
    __shared__ __align__(16) float ring1[RINGR][LDSW];
    __shared__ __align__(16) float ring2[RINGR][LDSW];
    __shared__ __align__(16) float ringm[RINGR][LDSW];
    __shared__ __align__(16) float fld[6][SUP][LDSW];
    __shared__ float redn[4], redd[4];

    const int tid = threadIdx.x;
    const int bc = blockIdx.z;
    const int b = bc / CHANS;
    const int c = bc - b * CHANS;
    const int ystart = blockIdx.y * FBSTRIPH;
    const int bx0 = blockIdx.x * STRIPW - 8;

    const float* p1 = img1 + (size_t)(b * CHANS + c) * (IMH * IMW);
    const float* p2 = img2 + (size_t)(b * CHANS + c) * (IMH * IMW);
    const float* pm = match + (size_t)b * (IMH * IMW);

    float g[11];
    {
        float s = 0.0f;
        #pragma unroll
        for (int i = 0; i < 11; ++i) {
            float d = (float)(i - 5);
            g[i] = expf(-(d * d) / 4.5f);
            s += g[i];
        }
        #pragma unroll
        for (int i = 0; i < 11; ++i) g[i] /= s;
    }

    float num = 0.0f, den = 0.0f;

    auto stage = [&](int gy0, int nrows) {
        for (int t = tid; t < nrows * NQ; t += 256) {
            int r = t / NQ, q = t - r * NQ;
            int gy = gy0 + r;
            int slot = (gy + 36) % RINGR;
            int gx = bx0 + 4 * q;
            float4 v1, v2, vm;
            if ((unsigned)gy < IMH && (unsigned)gx <= (IMW - 4)) {
                v1 = ld4s(p1 + gy * IMW + gx);
                v2 = ld4s(p2 + gy * IMW + gx);
                vm = ld4s(pm + gy * IMW + gx);
            } else if ((unsigned)gy < IMH) {
                float t1[4], t2[4], tm[4];
                #pragma unroll
                for (int e = 0; e < 4; ++e) {
                    int x = gx + e;
                    bool ok = (unsigned)x < IMW;
                    int off = gy * IMW + (ok ? x : 0);
                    t1[e] = ok ? p1[off] : 0.0f;
                    t2[e] = ok ? p2[off] : 0.0f;
                    tm[e] = ok ? pm[off] : 0.0f;
                }
                v1 = make_float4(t1[0], t1[1], t1[2], t1[3]);
                v2 = make_float4(t2[0], t2[1], t2[2], t2[3]);
                vm = make_float4(tm[0], tm[1], tm[2], tm[3]);
            } else {
                v1 = v2 = vm = make_float4(0.f, 0.f, 0.f, 0.f);
            }
            st4s(&ring1[slot][4 * q], v1);
            st4s(&ring2[slot][4 * q], v2);
            st4s(&ringm[slot][4 * q], vm);
        }
    };

    stage(ystart - 5, 10);

    for (int s = 0; s < FBNSUP; ++s) {
        const int ybase = ystart + s * SUP;
        stage(ybase + 5, SUP);
        __syncthreads();

        if (tid < SUP * NQ) {
            int r = tid / NQ, q = tid - r * NQ;
            int cq = 4 * q;
            int sr = (ybase + r + 31) % RINGR;
            float4 a1 = make_float4(0,0,0,0), a2 = a1, a3 = a1,
                   a4 = a1, a5 = a1, am = a1;
            #pragma unroll
            for (int k = 0; k < 11; ++k) {
                float4 x1 = ld4s(&ring1[sr][cq]);
                float4 x2 = ld4s(&ring2[sr][cq]);
                float4 xm = ld4s(&ringm[sr][cq]);
                float w = g[k];
                fma4(a1, w, x1);
                fma4(a2, w, x2);
                fma4m(a3, w, x1, x1);
                fma4m(a4, w, x2, x2);
                fma4m(a5, w, x1, x2);
                add4(am, xm);
                sr++; if (sr >= RINGR) sr -= RINGR;
            }
            st4s(&fld[0][r][cq], a1);
            st4s(&fld[1][r][cq], a2);
            st4s(&fld[2][r][cq], a3);
            st4s(&fld[3][r][cq], a4);
            st4s(&fld[4][r][cq], a5);
            st4s(&fld[5][r][cq], am);
        }
        __syncthreads();

        if (tid < SUP * 16) {
            int r = tid >> 4, q = tid & 15;
            int cb = 4 * q;
            float mu1[4], mu2[4], m11[4], m22[4], m12[4], mb[4];
            convg(fld[0][r], cb, g, mu1);
            convg(fld[1][r], cb, g, mu2);
            convg(fld[2][r], cb, g, m11);
            convg(fld[3][r], cb, g, m22);
            convg(fld[4][r], cb, g, m12);
            convb(fld[5][r], cb, mb);
            #pragma unroll
            for (int j = 0; j < 4; ++j) {
                float mu1s = mu1[j] * mu1[j];
                float mu2s = mu2[j] * mu2[j];
                float mu12 = mu1[j] * mu2[j];
                float sg1  = m11[j] - mu1s;
                float sg2  = m22[j] - mu2s;
                float sg12 = m12[j] - mu12;
                float ssim = ((2.0f * mu12 + 1e-4f) * (2.0f * sg12 + 9e-4f)) /
                             ((mu1s + mu2s + 1e-4f) * (sg1 + sg2 + 9e-4f));
                float m = mb[j] * (1.0f / 121.0f) + 1e-7f;
                float mask = (m > 0.5f) ? (1.0f + 1e-7f) : 1e-7f;
                num += (1.0f - ssim) * mask;
                den += mask;
            }
        }
    }

    for (int off = 32; off > 0; off >>= 1) {
        num += __shfl_down(num, off);
        den += __shfl_down(den, off);
    }
    int wave = tid >> 6;
    int lane = tid & 63;
    if (lane == 0) { redn[wave] = num; redd[wave] = den; }
    __syncthreads();
    if (tid == 0) {
        float n = redn[0] + redn[1] + redn[2] + redn[3];
        atomicAdd(&acc[0], (double)n);
        if (c == 0) {
            float d = redd[0] + redd[1] + redd[2] + redd[3];
            atomicAdd(&acc[1], (double)d);
        }
    }
}

__global__ void init_acc(double* acc, float* gw) {
    acc[0] = 0.0;
    acc[1] = 0.0;
    if (gw != nullptr) {
        // same expf sequence as the reference-matched in-kernel computation
        float t[11];
        float s = 0.0f;
        for (int i = 0; i < 11; ++i) {
            float d = (float)(i - 5);
            t[i] = expf(-(d * d) / 4.5f);
            s += t[i];
        }
        for (int i = 0; i < 11; ++i) gw[i] = t[i] / s;
    }
}

__global__ void finalize(const double* __restrict__ acc, float* __restrict__ out) {
    out[0] = (float)(acc[0] / acc[1] / 3.0);
}

extern "C" void kernel_launch(void* const* d_in, const int* in_sizes, int n_in,
                              void* d_out, int out_size, void* d_ws, size_t ws_size,
                              hipStream_t stream) {
    const float* img1  = (const float*)d_in[0];
    const float* img2  = (const float*)d_in[1];
    const float* match = (const float*)d_in[2];
    float* out = (float*)d_out;
    double* acc = (double*)d_ws;                       // 16 B @ ws+0

    const size_t mask_need = 128 + (size_t)BATCH * IMH * IMW;  // 4,194,432 B
    const bool premask = (ws_size >= mask_need);
    float* gw = premask ? (float*)((char*)d_ws + 64) : nullptr;  // 44 B @ ws+64

    init_acc<<<1, 1, 0, stream>>>(acc, gw);

    dim3 block(256, 1, 1);
    if (premask) {
        unsigned char* mbuf = (unsigned char*)d_ws + 128;
        dim3 mgrid(IMW / MTW, IMH / MTH, BATCH);               // 8 x 8 x 16
        mask_pass<<<mgrid, block, 0, stream>>>(match, mbuf, acc);
        dim3 grid(IMW / STRIPW, IMH / STRIPH, BATCH * CHANS);  // 8 x 8 x 48
        ssim_main_pm<<<grid, block, 0, stream>>>(img1, img2, mbuf, gw, acc);
    } else {
        dim3 grid(IMW / STRIPW, IMH / FBSTRIPH, BATCH * CHANS);
        ssim_main_fb<<<grid, block, 0, stream>>>(img1, img2, match, acc);
    }

    finalize<<<1, 1, 0, stream>>>(acc, out);
}

// Round 4
// 229.889 us; speedup vs baseline: 2.5712x; 1.1342x over previous
//
#include <hip/hip_runtime.h>

// SSIM_13443247637111 — fused separable SSIM, V-first ring-buffer design.
// B=16, CH=3, 512x512, 11x11 gaussian sigma 1.5, zero padding 5.
//
// Round-6 structure (occupancy via VGPR=64, float2 H phase):
//  - Empirical occupancy model from rounds 0-5: waves/SIMD = floor(256/VGPR).
//    VGPR 84 -> 3 waves/SIMD (31% occ); VGPR 40 -> 6 (62% occ, but spilled).
//    Target: VGPR = 64 exactly -> 4 waves/SIMD, no spills.
//  - __launch_bounds__(256, 4): caps allocator at floor(256/4) = 64 VGPR.
//  - H phase rewritten at float2 granularity over ALL 256 threads (8 rows x
//    32 half-quads). Window = 14 floats via 7 ds_read_b64 at compile-time
//    offsets (float4 version would need runtime window offset -> scratch).
//    Live set drops ~40 -> ~30 regs; V phase (~50) is now the peak.
//  - Premask design kept: mask_pass precomputes uint8 mask + denominator;
//    main kernel 2 rings + 5 fld = 25.6 KB LDS (not binding at 4 blocks/CU).
//  - Spill canary: FETCH ~107 MB / WRITE ~0.1 MB expected. If WRITE balloons,
//    the 64-squeeze spilled.

#define BATCH 16
#define CHANS 3
#define IMH 512
#define IMW 512
#define STRIPW 64
#define STRIPH 64
#define RINGR 18            // raw rows resident: y-5 .. y+12 for an 8-row super
#define LDSW 84             // padded row width; col c <-> x = bx*64 + c - 8
#define SUP 8               // output rows per super-iteration
#define NSUP (STRIPH / SUP) // 8
#define NQ 20               // float4 quads per staged row (80 cols)

// mask-pass tile
#define MTW 64
#define MTH 64
#define MRAWH 74            // MTH + 10 halo rows

__device__ __forceinline__ float4 ld4s(const float* p) { return *(const float4*)p; }
__device__ __forceinline__ void st4s(float* p, float4 v) { *(float4*)p = v; }
__device__ __forceinline__ void fma4(float4& a, float w, float4 x) {
    a.x = fmaf(w, x.x, a.x); a.y = fmaf(w, x.y, a.y);
    a.z = fmaf(w, x.z, a.z); a.w = fmaf(w, x.w, a.w);
}
__device__ __forceinline__ void fma4m(float4& a, float w, float4 x, float4 y) {
    a.x = fmaf(w, x.x * y.x, a.x); a.y = fmaf(w, x.y * y.y, a.y);
    a.z = fmaf(w, x.z * y.z, a.z); a.w = fmaf(w, x.w * y.w, a.w);
}
__device__ __forceinline__ void add4(float4& a, float4 x) {
    a.x += x.x; a.y += x.y; a.z += x.z; a.w += x.w;
}

// gaussian-weighted horizontal 11-tap conv: 4 outputs from 20-float window
// (used by mask_pass / fallback kernel only)
__device__ __forceinline__ void convg(const float* __restrict__ row, int cb,
                                      const float* __restrict__ g, float out[4]) {
    float w[20];
    #pragma unroll
    for (int i = 0; i < 5; ++i) {
        float4 v = ld4s(row + cb + 4 * i);
        w[4*i+0] = v.x; w[4*i+1] = v.y; w[4*i+2] = v.z; w[4*i+3] = v.w;
    }
    #pragma unroll
    for (int j = 0; j < 4; ++j) {
        float a = 0.0f;
        #pragma unroll
        for (int k = 0; k < 11; ++k) a = fmaf(g[k], w[3 + j + k], a);
        out[j] = a;
    }
}

// unweighted (box) horizontal 11-tap sum
__device__ __forceinline__ void convb(const float* __restrict__ row, int cb,
                                      float out[4]) {
    float w[20];
    #pragma unroll
    for (int i = 0; i < 5; ++i) {
        float4 v = ld4s(row + cb + 4 * i);
        w[4*i+0] = v.x; w[4*i+1] = v.y; w[4*i+2] = v.z; w[4*i+3] = v.w;
    }
    #pragma unroll
    for (int j = 0; j < 4; ++j) {
        float a = 0.0f;
        #pragma unroll
        for (int k = 0; k < 11; ++k) a += w[3 + j + k];
        out[j] = a;
    }
}

// ---------------------------------------------------------------------------
// mask precompute: box-filter match (11x11), threshold, store uint8 per pixel.
// Also accumulates the full denominator sum(mask) into acc[1].
// Grid 8x8x16 = 1024 blocks; ~21 MB of traffic, L2/L3-resident.
// ---------------------------------------------------------------------------
__global__ __launch_bounds__(256) void mask_pass(
    const float* __restrict__ match, unsigned char* __restrict__ maskbuf,
    double* __restrict__ acc)
{
    __shared__ __align__(16) float raw[MRAWH][LDSW];
    __shared__ __align__(16) float vs[MTH][LDSW];
    __shared__ float red[4];

    const int tid = threadIdx.x;
    const int b = blockIdx.z;
    const int x0 = blockIdx.x * MTW - 8;     // global x of LDS col 0 (aligned)
    const int y0 = blockIdx.y * MTH - 5;
    const float* pm = match + (size_t)b * (IMH * IMW);

    // stage 74 rows x 20 quads (cols x0 .. x0+79), zero pad OOB
    for (int t = tid; t < MRAWH * NQ; t += 256) {
        int r = t / NQ, q = t - r * NQ;
        int gy = y0 + r;
        int gx = x0 + 4 * q;
        float4 v = make_float4(0.f, 0.f, 0.f, 0.f);
        if ((unsigned)gy < IMH) {
            if ((unsigned)gx <= (IMW - 4)) {
                v = ld4s(pm + gy * IMW + gx);
            } else {
                float tmp[4];
                #pragma unroll
                for (int e = 0; e < 4; ++e) {
                    int x = gx + e;
                    bool ok = (unsigned)x < IMW;
                    tmp[e] = ok ? pm[gy * IMW + x] : 0.0f;
                }
                v = make_float4(tmp[0], tmp[1], tmp[2], tmp[3]);
            }
        }
        st4s(&raw[r][4 * q], v);
    }
    __syncthreads();

    // vertical box: 64 rows x 20 quads
    for (int t = tid; t < MTH * NQ; t += 256) {
        int r = t / NQ, q = t - r * NQ;
        int cq = 4 * q;
        float4 a = make_float4(0.f, 0.f, 0.f, 0.f);
        #pragma unroll
        for (int k = 0; k < 11; ++k) add4(a, ld4s(&raw[r + k][cq]));
        st4s(&vs[r][cq], a);
    }
    __syncthreads();

    // horizontal box + threshold: 64 rows x 16 quads
    float den = 0.0f;
    for (int t = tid; t < MTH * 16; t += 256) {
        int r = t >> 4, q = t & 15;
        float mb[4];
        convb(vs[r], 4 * q, mb);
        unsigned char bits[4];
        #pragma unroll
        for (int j = 0; j < 4; ++j) {
            float m = mb[j] * (1.0f / 121.0f) + 1e-7f;
            bool on = m > 0.5f;
            bits[j] = (unsigned char)on;
            den += on ? (1.0f + 1e-7f) : 1e-7f;
        }
        int gy = blockIdx.y * MTH + r;
        int gx = blockIdx.x * MTW + 4 * q;
        *(uchar4*)(maskbuf + ((size_t)b << 18) + (gy << 9) + gx) =
            make_uchar4(bits[0], bits[1], bits[2], bits[3]);
    }

    for (int off = 32; off > 0; off >>= 1) den += __shfl_down(den, off);
    if ((tid & 63) == 0) red[tid >> 6] = den;
    __syncthreads();
    if (tid == 0)
        atomicAdd(&acc[1], (double)(red[0] + red[1] + red[2] + red[3]));
}

// ---------------------------------------------------------------------------
// main SSIM kernel: 2 rings + 5 fld arrays, LDS 25.6 KB.
// __launch_bounds__(256,4): VGPR cap 64 -> 4 waves/SIMD (16 waves/CU).
// V phase: 160 threads x float4. H phase: 256 threads x float2.
// Grid 8x8x48 = 3072 blocks = exactly 12/CU.
// ---------------------------------------------------------------------------
__global__ __launch_bounds__(256, 4) void ssim_main_pm(
    const float* __restrict__ img1, const float* __restrict__ img2,
    const unsigned char* __restrict__ maskbuf,
    const float* __restrict__ gw, double* __restrict__ acc)
{
    __shared__ __align__(16) float ring1[RINGR][LDSW];
    __shared__ __align__(16) float ring2[RINGR][LDSW];
    __shared__ __align__(16) float fld[5][SUP][LDSW];
    __shared__ float redn[4];

    const int tid = threadIdx.x;
    const int bc = blockIdx.z;
    const int b = bc / CHANS;
    const int c = bc - b * CHANS;
    const int ystart = blockIdx.y * STRIPH;
    const int bxg = blockIdx.x;
    const int bx0 = bxg * STRIPW - 8;   // global x of LDS col 0

    const float* p1 = img1 + (size_t)(b * CHANS + c) * (IMH * IMW);
    const float* p2 = img2 + (size_t)(b * CHANS + c) * (IMH * IMW);
    const unsigned char* pmk = maskbuf + ((size_t)b << 18);

    // weights: uniform pointer + constant offsets -> scalar loads (SGPRs),
    // bit-identical to the expf sequence the reference-matched kernels used.
    float g[11];
    #pragma unroll
    for (int i = 0; i < 11; ++i) g[i] = gw[i];

    float num = 0.0f;
    const bool colsafe = (bx0 >= 0) && (bx0 + 4 * NQ <= IMW);  // interior in x

    auto stage = [&](int gy0, int nrows) {
        // nrows*NQ <= 200 < 256: single shot, no loop
        if (tid < nrows * NQ) {
            int r = tid / NQ, q = tid - r * NQ;
            int gy = gy0 + r;
            int slot = (gy + 36) % RINGR;
            int gx = bx0 + 4 * q;
            float4 v1 = make_float4(0.f, 0.f, 0.f, 0.f), v2 = v1;
            if ((unsigned)gy < IMH) {
                if (colsafe || (unsigned)gx <= (IMW - 4)) {
                    v1 = ld4s(p1 + gy * IMW + gx);
                    v2 = ld4s(p2 + gy * IMW + gx);
                } else {
                    float t1[4], t2[4];
                    #pragma unroll
                    for (int e = 0; e < 4; ++e) {
                        int x = gx + e;
                        bool ok = (unsigned)x < IMW;
                        int off = gy * IMW + (ok ? x : 0);
                        t1[e] = ok ? p1[off] : 0.0f;
                        t2[e] = ok ? p2[off] : 0.0f;
                    }
                    v1 = make_float4(t1[0], t1[1], t1[2], t1[3]);
                    v2 = make_float4(t2[0], t2[1], t2[2], t2[3]);
                }
            }
            st4s(&ring1[slot][4 * q], v1);
            st4s(&ring2[slot][4 * q], v2);
        }
    };

    // prologue: raw rows ystart-5 .. ystart+4
    stage(ystart - 5, 10);

    for (int s = 0; s < NSUP; ++s) {
        const int ybase = ystart + s * SUP;

        // stage the 8 new raw rows this super needs (ybase+5 .. ybase+12).
        // safe: slots being overwritten were last read by V of super s-1,
        // which completed before barrier B2 of super s-1.
        stage(ybase + 5, SUP);
        __syncthreads();   // B1: staging visible; fld free (H of s-1 done)

        // ---- vertical pass: 8 rows x 20 quads (80 cols incl. halo) ----
        if (tid < SUP * NQ) {
            int r = tid / NQ, q = tid - r * NQ;
            int cq = 4 * q;
            int sr = (ybase + r + 31) % RINGR;   // row (y-5)
            float4 a1 = make_float4(0,0,0,0), a2 = a1, a3 = a1,
                   a4 = a1, a5 = a1;
            #pragma unroll
            for (int k = 0; k < 11; ++k) {
                float4 x1 = ld4s(&ring1[sr][cq]);
                float4 x2 = ld4s(&ring2[sr][cq]);
                float w = g[k];
                fma4(a1, w, x1);
                fma4(a2, w, x2);
                fma4m(a3, w, x1, x1);
                fma4m(a4, w, x2, x2);
                fma4m(a5, w, x1, x2);
                sr++; if (sr >= RINGR) sr -= RINGR;
            }
            st4s(&fld[0][r][cq], a1);
            st4s(&fld[1][r][cq], a2);
            st4s(&fld[2][r][cq], a3);
            st4s(&fld[3][r][cq], a4);
            st4s(&fld[4][r][cq], a5);
        }
        __syncthreads();   // B2: fld visible; ring free for next stage

        // ---- horizontal pass + SSIM: 8 rows x 32 float2 cols, 256 thr ----
        {
            int r = tid >> 5, h = tid & 31;
            // outputs at strip cols 2h, 2h+1 (LDS cols 2h+8, 2h+9).
            // taps for out0: LDS cols 2h+3 .. 2h+13; out1: 2h+4 .. 2h+14.
            // load LDS cols 2h+2 .. 2h+15 as 7 float2 (8B aligned, constant
            // in-register offsets -> no runtime-indexed array -> no scratch).
            const int c0 = 2 * h + 2;
            float mu1[2], mu2[2], m11[2], m22[2], m12[2];
            auto convg2 = [&](const float* __restrict__ row, float out[2]) {
                float wf[14];
                #pragma unroll
                for (int i = 0; i < 7; ++i) {
                    float2 v = *(const float2*)(row + c0 + 2 * i);
                    wf[2*i]   = v.x;
                    wf[2*i+1] = v.y;
                }
                float a0 = 0.0f, a1 = 0.0f;
                #pragma unroll
                for (int k = 0; k < 11; ++k) {
                    a0 = fmaf(g[k], wf[1 + k], a0);
                    a1 = fmaf(g[k], wf[2 + k], a1);
                }
                out[0] = a0; out[1] = a1;
            };
            convg2(fld[0][r], mu1);
            convg2(fld[1][r], mu2);
            convg2(fld[2][r], m11);
            convg2(fld[3][r], m22);
            convg2(fld[4][r], m12);

            int gy = ybase + r;
            int gx = bxg * STRIPW + 2 * h;
            uchar2 mk = *(const uchar2*)(pmk + (gy << 9) + gx);
            const unsigned char mkv[2] = {mk.x, mk.y};
            #pragma unroll
            for (int j = 0; j < 2; ++j) {
                float mu1s = mu1[j] * mu1[j];
                float mu2s = mu2[j] * mu2[j];
                float mu12 = mu1[j] * mu2[j];
                float sg1  = m11[j] - mu1s;
                float sg2  = m22[j] - mu2s;
                float sg12 = m12[j] - mu12;
                float ssim = ((2.0f * mu12 + 1e-4f) * (2.0f * sg12 + 9e-4f)) /
                             ((mu1s + mu2s + 1e-4f) * (sg1 + sg2 + 9e-4f));
                float mask = mkv[j] ? (1.0f + 1e-7f) : 1e-7f;
                num += (1.0f - ssim) * mask;
            }
        }
    }

    // ---- block reduction: wave shuffle (width 64) then cross-wave LDS ----
    for (int off = 32; off > 0; off >>= 1) num += __shfl_down(num, off);
    if ((tid & 63) == 0) redn[tid >> 6] = num;
    __syncthreads();
    if (tid == 0)
        atomicAdd(&acc[0], (double)(redn[0] + redn[1] + redn[2] + redn[3]));
    (void)c;
}

// ---------------------------------------------------------------------------
// fallback: round-2 all-in-one kernel (used only if ws too small for mask)
// ---------------------------------------------------------------------------
#define FBSTRIPH 256
#define FBNSUP (FBSTRIPH / SUP)
__global__ __launch_bounds__(256) void ssim_main_fb(
    const float* __restrict__ img1, const float* __restrict__ img2,
    const float* __restrict__ match, double* __restrict__ acc)
{
    __shared__ __align__(16) float ring1[RINGR][LDSW];
    __shared__ __align__(16) float ring2[RINGR][LDSW];
    __shared__ __align__(16) float ringm[RINGR][LDSW];
    __shared__ __align__(16) float fld[6][SUP][LDSW];
    __shared__ float redn[4], redd[4];

    const int tid = threadIdx.x;
    const int bc = blockIdx.z;
    const int b = bc / CHANS;
    const int c = bc - b * CHANS;
    const int ystart = blockIdx.y * FBSTRIPH;
    const int bx0 = blockIdx.x * STRIPW - 8;

    const float* p1 = img1 + (size_t)(b * CHANS + c) * (IMH * IMW);
    const float* p2 = img2 + (size_t)(b * CHANS + c) * (IMH * IMW);
    const float* pm = match + (size_t)b * (IMH * IMW);

    float g[11];
    {
        float s = 0.0f;
        #pragma unroll
        for (int i = 0; i < 11; ++i) {
            float d = (float)(i - 5);
            g[i] = expf(-(d * d) / 4.5f);
            s += g[i];
        }
        #pragma unroll
        for (int i = 0; i < 11; ++i) g[i] /= s;
    }

    float num = 0.0f, den = 0.0f;

    auto stage = [&](int gy0, int nrows) {
        for (int t = tid; t < nrows * NQ; t += 256) {
            int r = t / NQ, q = t - r * NQ;
            int gy = gy0 + r;
            int slot = (gy + 36) % RINGR;
            int gx = bx0 + 4 * q;
            float4 v1, v2, vm;
            if ((unsigned)gy < IMH && (unsigned)gx <= (IMW - 4)) {
                v1 = ld4s(p1 + gy * IMW + gx);
                v2 = ld4s(p2 + gy * IMW + gx);
                vm = ld4s(pm + gy * IMW + gx);
            } else if ((unsigned)gy < IMH) {
                float t1[4], t2[4], tm[4];
                #pragma unroll
                for (int e = 0; e < 4; ++e) {
                    int x = gx + e;
                    bool ok = (unsigned)x < IMW;
                    int off = gy * IMW + (ok ? x : 0);
                    t1[e] = ok ? p1[off] : 0.0f;
                    t2[e] = ok ? p2[off] : 0.0f;
                    tm[e] = ok ? pm[off] : 0.0f;
                }
                v1 = make_float4(t1[0], t1[1], t1[2], t1[3]);
                v2 = make_float4(t2[0], t2[1], t2[2], t2[3]);
                vm = make_float4(tm[0], tm[1], tm[2], tm[3]);
            } else {
                v1 = v2 = vm = make_float4(0.f, 0.f, 0.f, 0.f);
            }
            st4s(&ring1[slot][4 * q], v1);
            st4s(&ring2[slot][4 * q], v2);
            st4s(&ringm[slot][4 * q], vm);
        }
    };

    stage(ystart - 5, 10);

    for (int s = 0; s < FBNSUP; ++s) {
        const int ybase = ystart + s * SUP;
        stage(ybase + 5, SUP);
        __syncthreads();

        if (tid < SUP * NQ) {
            int r = tid / NQ, q = tid - r * NQ;
            int cq = 4 * q;
            int sr = (ybase + r + 31) % RINGR;
            float4 a1 = make_float4(0,0,0,0), a2 = a1, a3 = a1,
                   a4 = a1, a5 = a1, am = a1;
            #pragma unroll
            for (int k = 0; k < 11; ++k) {
                float4 x1 = ld4s(&ring1[sr][cq]);
                float4 x2 = ld4s(&ring2[sr][cq]);
                float4 xm = ld4s(&ringm[sr][cq]);
                float w = g[k];
                fma4(a1, w, x1);
                fma4(a2, w, x2);
                fma4m(a3, w, x1, x1);
                fma4m(a4, w, x2, x2);
                fma4m(a5, w, x1, x2);
                add4(am, xm);
                sr++; if (sr >= RINGR) sr -= RINGR;
            }
            st4s(&fld[0][r][cq], a1);
            st4s(&fld[1][r][cq], a2);
            st4s(&fld[2][r][cq], a3);
            st4s(&fld[3][r][cq], a4);
            st4s(&fld[4][r][cq], a5);
            st4s(&fld[5][r][cq], am);
        }
        __syncthreads();

        if (tid < SUP * 16) {
            int r = tid >> 4, q = tid & 15;
            int cb = 4 * q;
            float mu1[4], mu2[4], m11[4], m22[4], m12[4], mb[4];
            convg(fld[0][r], cb, g, mu1);
            convg(fld[1][r], cb, g, mu2);
            convg(fld[2][r], cb, g, m11);
            convg(fld[3][r], cb, g, m22);
            convg(fld[4][r], cb, g, m12);
            convb(fld[5][r], cb, mb);
            #pragma unroll
            for (int j = 0; j < 4; ++j) {
                float mu1s = mu1[j] * mu1[j];
                float mu2s = mu2[j] * mu2[j];
                float mu12 = mu1[j] * mu2[j];
                float sg1  = m11[j] - mu1s;
                float sg2  = m22[j] - mu2s;
                float sg12 = m12[j] - mu12;
                float ssim = ((2.0f * mu12 + 1e-4f) * (2.0f * sg12 + 9e-4f)) /
                             ((mu1s + mu2s + 1e-4f) * (sg1 + sg2 + 9e-4f));
                float m = mb[j] * (1.0f / 121.0f) + 1e-7f;
                float mask = (m > 0.5f) ? (1.0f + 1e-7f) : 1e-7f;
                num += (1.0f - ssim) * mask;
                den += mask;
            }
        }
    }

    for (int off = 32; off > 0; off >>= 1) {
        num += __shfl_down(num, off);
        den += __shfl_down(den, off);
    }
    int wave = tid >> 6;
    int lane = tid & 63;
    if (lane == 0) { redn[wave] = num; redd[wave] = den; }
    __syncthreads();
    if (tid == 0) {
        float n = redn[0] + redn[1] + redn[2] + redn[3];
        atomicAdd(&acc[0], (double)n);
        if (c == 0) {
            float d = redd[0] + redd[1] + redd[2] + redd[3];
            atomicAdd(&acc[1], (double)d);
        }
    }
}

__global__ void init_acc(double* acc, float* gw) {
    acc[0] = 0.0;
    acc[1] = 0.0;
    if (gw != nullptr) {
        // same expf sequence as the reference-matched in-kernel computation
        float t[11];
        float s = 0.0f;
        for (int i = 0; i < 11; ++i) {
            float d = (float)(i - 5);
            t[i] = expf(-(d * d) / 4.5f);
            s += t[i];
        }
        for (int i = 0; i < 11; ++i) gw[i] = t[i] / s;
    }
}

__global__ void finalize(const double* __restrict__ acc, float* __restrict__ out) {
    out[0] = (float)(acc[0] / acc[1] / 3.0);
}

extern "C" void kernel_launch(void* const* d_in, const int* in_sizes, int n_in,
                              void* d_out, int out_size, void* d_ws, size_t ws_size,
                              hipStream_t stream) {
    const float* img1  = (const float*)d_in[0];
    const float* img2  = (const float*)d_in[1];
    const float* match = (const float*)d_in[2];
    float* out = (float*)d_out;
    double* acc = (double*)d_ws;                       // 16 B @ ws+0

    const size_t mask_need = 128 + (size_t)BATCH * IMH * IMW;  // 4,194,432 B
    const bool premask = (ws_size >= mask_need);
    float* gw = premask ? (float*)((char*)d_ws + 64) : nullptr;  // 44 B @ ws+64

    init_acc<<<1, 1, 0, stream>>>(acc, gw);

    dim3 block(256, 1, 1);
    if (premask) {
        unsigned char* mbuf = (unsigned char*)d_ws + 128;
        dim3 mgrid(IMW / MTW, IMH / MTH, BATCH);               // 8 x 8 x 16
        mask_pass<<<mgrid, block, 0, stream>>>(match, mbuf, acc);
        dim3 grid(IMW / STRIPW, IMH / STRIPH, BATCH * CHANS);  // 8 x 8 x 48
        ssim_main_pm<<<grid, block, 0, stream>>>(img1, img2, mbuf, gw, acc);
    } else {
        dim3 grid(IMW / STRIPW, IMH / FBSTRIPH, BATCH * CHANS);
        ssim_main_fb<<<grid, block, 0, stream>>>(img1, img2, match, acc);
    }

    finalize<<<1, 1, 0, stream>>>(acc, out);
}